// Round 8
// baseline (161.276 us; speedup 1.0000x reference)
//
#include <hip/hip_runtime.h>
#include <hip/hip_bf16.h>

// Problem constants
#define IN_C   64
#define OUT_D  47          // (24-1)*2 - 2*1 + 3
#define XD     24
#define XSP    (XD*XD*XD)  // 13824
#define OSP    (OUT_D*OUT_D*OUT_D) // 103823
#define BATCH  16

typedef short  short8  __attribute__((ext_vector_type(8)));
typedef float  floatx4 __attribute__((ext_vector_type(4)));
typedef float  f4u     __attribute__((ext_vector_type(4), aligned(4)));

__device__ __forceinline__ unsigned pk2(float a, float b) {
    unsigned lo = (unsigned)__builtin_bit_cast(unsigned short, __float2bfloat16(a));
    unsigned hi = (unsigned)__builtin_bit_cast(unsigned short, __float2bfloat16(b));
    return lo | (hi << 16);
}

// B-fragment prep. Tap-major K: k = t*64 + c, t = td*9+th*3+tw (tap offsets -1..1
// per dim as index 0..2). Per-dim weight masks (bit z of w):
//   p=0: t0:{w2}=4, t1:{w0,w1}=3, t2:{}=0 ;  p=1: t0:{}=0, t1:{w1,w2}=6, t2:{w0}=1
// Fragment for 16x16x32 bf16: lane (n=L&15, kg=L>>4) holds B[k=kg*8+j][n], j=0..7,
// packed as 4 u32 (j-pairs, low half = even j). n>=8 -> zeros (N padding).
__global__ void wfrag_prep(const float* __restrict__ w, uint4* __restrict__ wfrag) {
    const int b = blockIdx.x;        // 0..53 = t*2 + chunk
    const int t = b >> 1, chunk = b & 1;
    const int td = t / 9, th = (t / 3) % 3, twi = t % 3;
    const int L = threadIdx.x;
    const int n = L & 15, kg = L >> 4;
    unsigned vals[4] = {0u, 0u, 0u, 0u};
    if (n < 8) {
        const int pd = n >> 2, ph = (n >> 1) & 1, pw = n & 1;
        const int Mm[2][3] = {{4, 3, 0}, {0, 6, 1}};
        const int mz = Mm[pd][td], my = Mm[ph][th], mx = Mm[pw][twi];
        float v[8];
        #pragma unroll
        for (int j = 0; j < 8; j++) {
            int c = chunk * 32 + kg * 8 + j;
            const float* wc = w + (size_t)c * 64 * 27;   // weight[c][0][*]
            float s = 0.f;
            for (int zd = 0; zd < 3; zd++) if ((mz >> zd) & 1)
                for (int zh = 0; zh < 3; zh++) if ((my >> zh) & 1)
                    for (int zw = 0; zw < 3; zw++) if ((mx >> zw) & 1)
                        s += wc[zd * 9 + zh * 3 + zw];
            v[j] = s;
        }
        #pragma unroll
        for (int i = 0; i < 4; i++) vals[i] = pk2(v[2 * i], v[2 * i + 1]);
    }
    wfrag[b * 64 + L] = make_uint4(vals[0], vals[1], vals[2], vals[3]);
}

// Main MFMA kernel. 864 blocks = 54 sp-tiles (m-tile 4x8x8) x 16 n (n in low
// bits). 256 threads = 4 waves; wave wv owns m-d slab md=wv with FULL K
// (no reduction). LDS tile: halo 6z x 10y x 10x voxels, record = 64B = 32
// bf16 channels (one chunk), row stride 11 records, sub-block swizzle
// (kg + xt + (xt>>2) + (r>>1)) & 3  -> conflict-free write AND read phases.
// Two chunk phases (c 0..31, 32..63) re-stage the same tile.
#define NRECROW 11
#define LDSQ (60 * NRECROW * 4)   // uint4 count = 2640 (42.24 KB)

__global__ __launch_bounds__(256) void tconv(const float* __restrict__ x,
                                             const uint4* __restrict__ wfrag,
                                             const float* __restrict__ bias,
                                             float* __restrict__ out) {
    __shared__ uint4 lds4[LDSQ];
    const int blk = blockIdx.x;
    const int n = blk & 15;
    const int sp = blk >> 4;         // 0..53
    const int tz = sp / 9;
    const int r9 = sp - tz * 9;
    const int ty = r9 / 3;
    const int tx = r9 - ty * 3;
    const int Bd = tz * 4, Bh = ty * 8, Bw = tx * 8;

    const int tid = threadIdx.x;
    const int wv = tid >> 6;         // md slab
    const int L  = tid & 63;
    const int mL = L & 15, kgL = L >> 4;

    // zero-fill whole tile once (invalid halo rows must read as 0)
    for (int i = tid; i < LDSQ; i += 256) lds4[i] = make_uint4(0, 0, 0, 0);

    // ---- staging descriptors: units e = (kg*3+u)*60 + r, 3 per thread ----
    int ur[3], uu[3], ukg[3], uet[3], ugofs[3];
    #pragma unroll
    for (int k = 0; k < 3; k++) {
        int e = tid + 256 * k;
        int r = e % 60, q = e / 60, u = q % 3, kg = q / 3;
        int z = r / 10, y = r - 10 * z;
        int gz = Bd - 1 + z, gy = Bh - 1 + y;
        bool rv = (e < 720) && ((unsigned)gz < (unsigned)XD) &&
                  ((unsigned)gy < (unsigned)XD);
        int gxs = Bw - 1 + 4 * u;
        int et;
        if (!rv) et = -1;
        else if (gxs < 0) et = 1;            // Bw=0,u=0: gx -1..2
        else if (gxs + 3 > XD - 1) et = 2;   // Bw=16,u=2: gx 23..26
        else et = 0;
        ur[k] = r; uu[k] = u; ukg[k] = kg; uet[k] = et;
        ugofs[k] = (gz * XD + gy) * XD + (gxs < 0 ? 0 : gxs);
    }

    floatx4 acc[4] = {{0.f,0.f,0.f,0.f},{0.f,0.f,0.f,0.f},
                      {0.f,0.f,0.f,0.f},{0.f,0.f,0.f,0.f}};

    #pragma unroll 1
    for (int chunk = 0; chunk < 2; chunk++) {
        __syncthreads();   // zero-fill done / previous mfma phase done

        // ---- stage: fp32 global -> bf16-pair LDS records ----
        #pragma unroll
        for (int k = 0; k < 3; k++) {
            if (uet[k] < 0) continue;
            const float* xc = x + ((size_t)(n * IN_C + chunk * 32 + ukg[k] * 8)) * XSP
                                + ugofs[k];
            float4 q[8];
            if (uet[k] == 2) {
                #pragma unroll
                for (int c = 0; c < 8; c++)
                    q[c] = make_float4(xc[c * XSP], 0.f, 0.f, 0.f);
            } else {
                #pragma unroll
                for (int c = 0; c < 8; c++) {
                    f4u v = *(const f4u*)(xc + c * XSP);
                    q[c] = make_float4(v.x, v.y, v.z, v.w);
                }
                if (uet[k] == 1) {
                    #pragma unroll
                    for (int c = 0; c < 8; c++)
                        q[c] = make_float4(0.f, q[c].x, q[c].y, q[c].z);
                }
            }
            const int r = ur[k], u = uu[k], kg = ukg[k];
            #define QEL(c, i) ((i) == 0 ? q[c].x : (i) == 1 ? q[c].y : (i) == 2 ? q[c].z : q[c].w)
            #pragma unroll
            for (int i = 0; i < 4; i++) {
                int xt = 4 * u + i;
                if (xt < 10) {
                    unsigned p0 = pk2(QEL(0, i), QEL(1, i));
                    unsigned p1 = pk2(QEL(2, i), QEL(3, i));
                    unsigned p2 = pk2(QEL(4, i), QEL(5, i));
                    unsigned p3 = pk2(QEL(6, i), QEL(7, i));
                    int sub = (kg + xt + (xt >> 2) + (r >> 1)) & 3;
                    lds4[(r * NRECROW + xt) * 4 + sub] = make_uint4(p0, p1, p2, p3);
                }
            }
            #undef QEL
        }
        __syncthreads();

        // ---- MFMA phase: 27 taps x 4 m-groups ----
        #pragma unroll 1
        for (int t = 0; t < 27; t++) {
            uint4 bw = wfrag[(t * 2 + chunk) * 64 + L];
            short8 Bf = __builtin_bit_cast(short8, bw);
            const int td = t / 9, rem = t - 9 * td, th = rem / 3, tw = rem - 3 * th;
            #pragma unroll
            for (int g = 0; g < 4; g++) {
                int rr = (wv + td) * 10 + 2 * g + (mL >> 3) + th;
                int xt = (mL & 7) + tw;
                int sub = (kgL + xt + (xt >> 2) + (rr >> 1)) & 3;
                short8 Af = __builtin_bit_cast(short8,
                                lds4[(rr * NRECROW + xt) * 4 + sub]);
                acc[g] = __builtin_amdgcn_mfma_f32_16x16x32_bf16(Af, Bf, acc[g], 0, 0, 0);
            }
        }
    }

    // ---- epilogue: D[m = (L>>4)*4+reg][n = L&15]; n<8 = parity (pd,ph,pw) ----
    if (mL < 8) {
        const int pd = mL >> 2, ph = (mL >> 1) & 1, pw = mL & 1;
        const float bterm = bias[0] * 64.0f;
        float* on = out + (size_t)n * OSP;
        const int od = 2 * (Bd + wv) + pd;
        if (od < OUT_D) {
            #pragma unroll
            for (int g = 0; g < 4; g++) {
                #pragma unroll
                for (int r4 = 0; r4 < 4; r4++) {
                    int m = kgL * 4 + r4;
                    int mh2 = m >> 3, mw = m & 7;
                    int oh = 2 * (Bh + 2 * g + mh2) + ph;
                    int ow = 2 * (Bw + mw) + pw;
                    if (oh < OUT_D && ow < OUT_D)
                        on[(od * OUT_D + oh) * OUT_D + ow] = acc[g][r4] * 64.0f + bterm;
                }
            }
        }
    }
}

extern "C" void kernel_launch(void* const* d_in, const int* in_sizes, int n_in,
                              void* d_out, int out_size, void* d_ws, size_t ws_size,
                              hipStream_t stream) {
    const float* x      = (const float*)d_in[0];
    const float* weight = (const float*)d_in[1];
    const float* bias   = (const float*)d_in[2];
    float* out = (float*)d_out;
    uint4* wfrag = (uint4*)d_ws;       // 54*64*16B = 55,296 bytes

    hipLaunchKernelGGL(wfrag_prep, dim3(54), dim3(64), 0, stream, weight, wfrag);

    dim3 grid(54 * BATCH, 1, 1);       // 864 blocks, n in low 4 bits
    hipLaunchKernelGGL(tconv, grid, dim3(256), 0, stream, x, wfrag, bias, out);
}